// Round 3
// baseline (200.475 us; speedup 1.0000x reference)
//
#include <hip/hip_runtime.h>

// AttentionHead: B=4, T=4096, C=1024, H=64, causal softmax(QK^T/8)V
// bf16 MFMA (16x16x32) for proj + flash attention, fp32 accumulation.
// Adaptive ws footprint (round-2 post-timing divergence root-caused as
// probable d_ws overflow corrupting an input):
//   Plan A (ws >= 6.29MB): Kr | Vt | Qs   (3 x 2MB bf16)
//   Plan B (ws >= 4.19MB): Kr | Vt        (2 x 2MB bf16), attn recomputes Q

using bf16x8 = __attribute__((ext_vector_type(8))) short;
using bf16x4 = __attribute__((ext_vector_type(4))) short;
using f32x4  = __attribute__((ext_vector_type(4))) float;

__device__ __forceinline__ unsigned short f2bf(float f) {
  union { float f; unsigned int u; } v; v.f = f;
  unsigned int r = v.u + 0x7fffu + ((v.u >> 16) & 1u);  // RNE
  return (unsigned short)(r >> 16);
}

// ---- projections: 64 rows x (K[,Q],V) cols per block, K=1024 ----------
// W staged from fp32 global with inline transpose (coalesced reads).
template <bool WRITE_Q>
__global__ __launch_bounds__(256) void proj_kernel(
    const float* __restrict__ X,  const float* __restrict__ Wk,
    const float* __restrict__ Wq, const float* __restrict__ Wv,
    const float* __restrict__ bk, const float* __restrict__ bq,
    const float* __restrict__ bv, unsigned short* __restrict__ Kr,
    unsigned short* __restrict__ Qs, unsigned short* __restrict__ Vt) {
  constexpr int NT = WRITE_Q ? 12 : 8;   // 16-col tiles: K(4) [,Q(4)], V(4)
  constexpr int NC = NT / 4;             // 64-col chunks
  __shared__ __align__(16) unsigned short Xl[64 * 72];
  __shared__ __align__(16) unsigned short Wl[NT * 16 * 72];
  const int tid = threadIdx.x;
  const int m0  = blockIdx.x * 64;
  const int w   = tid >> 6;
  const int ln  = tid & 63;
  const int l15 = ln & 15;
  const int l4  = ln >> 4;
  const f32x4 zero4 = {0.f, 0.f, 0.f, 0.f};

  f32x4 acc[NT];
  #pragma unroll
  for (int i = 0; i < NT; ++i) acc[i] = zero4;

  const int wn = tid & 63;          // W-transpose staging coords
  const int wk = (tid >> 6) * 16;

  for (int kb = 0; kb < 16; ++kb) {
    __syncthreads();
    #pragma unroll
    for (int p = 0; p < 4; ++p) {   // stage X 64x64 fp32 -> bf16
      int chunk = tid + p * 256;
      int r = chunk >> 4, c4 = chunk & 15;
      const float4 xv = *reinterpret_cast<const float4*>(
          X + (size_t)(m0 + r) * 1024 + kb * 64 + c4 * 4);
      bf16x4 o;
      o[0] = (short)f2bf(xv.x); o[1] = (short)f2bf(xv.y);
      o[2] = (short)f2bf(xv.z); o[3] = (short)f2bf(xv.w);
      *reinterpret_cast<bf16x4*>(&Xl[r * 72 + c4 * 4]) = o;
    }
    #pragma unroll
    for (int c = 0; c < NC; ++c) {  // stage W chunk transposed: Wl[n][k]
      const float* Wsrc = (c == 0) ? Wk : ((WRITE_Q && c == 1) ? Wq : Wv);
      bf16x8 w0, w1;
      #pragma unroll
      for (int j = 0; j < 8; ++j)
        w0[j] = (short)f2bf(Wsrc[(size_t)(kb * 64 + wk + j) * 64 + wn]);
      #pragma unroll
      for (int j = 0; j < 8; ++j)
        w1[j] = (short)f2bf(Wsrc[(size_t)(kb * 64 + wk + 8 + j) * 64 + wn]);
      *reinterpret_cast<bf16x8*>(&Wl[(c * 64 + wn) * 72 + wk])     = w0;
      *reinterpret_cast<bf16x8*>(&Wl[(c * 64 + wn) * 72 + wk + 8]) = w1;
    }
    __syncthreads();
    bf16x8 a0 = *reinterpret_cast<const bf16x8*>(&Xl[(w * 16 + l15) * 72 + l4 * 8]);
    bf16x8 a1 = *reinterpret_cast<const bf16x8*>(&Xl[(w * 16 + l15) * 72 + 32 + l4 * 8]);
    #pragma unroll
    for (int nt = 0; nt < NT; ++nt) {
      bf16x8 b0 = *reinterpret_cast<const bf16x8*>(&Wl[(nt * 16 + l15) * 72 + l4 * 8]);
      bf16x8 b1 = *reinterpret_cast<const bf16x8*>(&Wl[(nt * 16 + l15) * 72 + 32 + l4 * 8]);
      acc[nt] = __builtin_amdgcn_mfma_f32_16x16x32_bf16(a0, b0, acc[nt], 0, 0, 0);
      acc[nt] = __builtin_amdgcn_mfma_f32_16x16x32_bf16(a1, b1, acc[nt], 0, 0, 0);
    }
  }
  #pragma unroll
  for (int nt = 0; nt < NT; ++nt) {
    int j = nt * 16 + l15;
    #pragma unroll
    for (int r = 0; r < 4; ++r) {
      int m = m0 + w * 16 + l4 * 4 + r;   // D row = 4*(lane>>4)+reg
      float v = acc[nt][r];
      if (nt < 4) {
        Kr[(size_t)m * 64 + j] = f2bf(v + bk[j]);
      } else if (WRITE_Q && nt < 8) {
        Qs[(size_t)m * 64 + (j - 64)] = f2bf((v + bq[j - 64]) * 0.125f);
      } else {
        int h = j - (WRITE_Q ? 128 : 64);
        int bb = m >> 12, t = m & 4095;
        Vt[((size_t)(bb * 64 + h)) * 4096 + t] = f2bf(v + bv[h]);
      }
    }
  }
}

// ---- flash attention, causal; 1 block = 64 q rows, 4 waves x 16 rows --
template <bool RECOMPUTE_Q>
__global__ __launch_bounds__(256) void attn_kernel(
    const unsigned short* __restrict__ Qs,   // unused if RECOMPUTE_Q
    const unsigned short* __restrict__ Kr,
    const unsigned short* __restrict__ Vt,
    const float* __restrict__ X, const float* __restrict__ Wq,
    const float* __restrict__ bq, float* __restrict__ out) {
  __shared__ __align__(16) unsigned short Kl[64 * 72];       // [kv][h] (or X stage)
  __shared__ __align__(16) unsigned short Vl[64 * 72];       // [h][kv] (or Wq stage)
  __shared__ __align__(16) unsigned short Pl[4 * 16 * 72];   // per-wave [q][kv]
  const int tid = threadIdx.x;
  const int w   = tid >> 6;
  const int ln  = tid & 63;
  const int l15 = ln & 15;
  const int l4  = ln >> 4;
  const int b   = blockIdx.y;
  const int q0  = blockIdx.x * 64;
  const int qrow = q0 + w * 16;
  const f32x4 zero4 = {0.f, 0.f, 0.f, 0.f};
  unsigned short* Pw = &Pl[w * 16 * 72];

  bf16x8 qa0, qa1;
  if constexpr (!RECOMPUTE_Q) {
    const unsigned short* Qbase = Qs + ((size_t)b * 4096 + qrow + l15) * 64;
    qa0 = *reinterpret_cast<const bf16x8*>(Qbase + l4 * 8);
    qa1 = *reinterpret_cast<const bf16x8*>(Qbase + 32 + l4 * 8);
  } else {
    // Phase 0: Q-tile = X[rows q0..q0+63] @ Wq, reusing Kl (X) and Vl (Wq^T)
    f32x4 accq[4];
    #pragma unroll
    for (int i = 0; i < 4; ++i) accq[i] = zero4;
    const int wn = tid & 63;
    const int wk = (tid >> 6) * 16;
    for (int kb = 0; kb < 16; ++kb) {
      __syncthreads();
      #pragma unroll
      for (int p = 0; p < 4; ++p) {
        int chunk = tid + p * 256;
        int r = chunk >> 4, c4 = chunk & 15;
        const float4 xv = *reinterpret_cast<const float4*>(
            X + ((size_t)b * 4096 + q0 + r) * 1024 + kb * 64 + c4 * 4);
        bf16x4 o;
        o[0] = (short)f2bf(xv.x); o[1] = (short)f2bf(xv.y);
        o[2] = (short)f2bf(xv.z); o[3] = (short)f2bf(xv.w);
        *reinterpret_cast<bf16x4*>(&Kl[r * 72 + c4 * 4]) = o;
      }
      bf16x8 w0, w1;
      #pragma unroll
      for (int j = 0; j < 8; ++j)
        w0[j] = (short)f2bf(Wq[(size_t)(kb * 64 + wk + j) * 64 + wn]);
      #pragma unroll
      for (int j = 0; j < 8; ++j)
        w1[j] = (short)f2bf(Wq[(size_t)(kb * 64 + wk + 8 + j) * 64 + wn]);
      *reinterpret_cast<bf16x8*>(&Vl[wn * 72 + wk])     = w0;
      *reinterpret_cast<bf16x8*>(&Vl[wn * 72 + wk + 8]) = w1;
      __syncthreads();
      bf16x8 a0 = *reinterpret_cast<const bf16x8*>(&Kl[(w * 16 + l15) * 72 + l4 * 8]);
      bf16x8 a1 = *reinterpret_cast<const bf16x8*>(&Kl[(w * 16 + l15) * 72 + 32 + l4 * 8]);
      #pragma unroll
      for (int nt = 0; nt < 4; ++nt) {
        bf16x8 b0 = *reinterpret_cast<const bf16x8*>(&Vl[(nt * 16 + l15) * 72 + l4 * 8]);
        bf16x8 b1 = *reinterpret_cast<const bf16x8*>(&Vl[(nt * 16 + l15) * 72 + 32 + l4 * 8]);
        accq[nt] = __builtin_amdgcn_mfma_f32_16x16x32_bf16(a0, b0, accq[nt], 0, 0, 0);
        accq[nt] = __builtin_amdgcn_mfma_f32_16x16x32_bf16(a1, b1, accq[nt], 0, 0, 0);
      }
    }
    // D-layout -> A-layout via per-wave LDS round-trip (+bias, pre-scale)
    #pragma unroll
    for (int nt = 0; nt < 4; ++nt) {
      int h = nt * 16 + l15;
      #pragma unroll
      for (int r = 0; r < 4; ++r)
        Pw[(l4 * 4 + r) * 72 + h] = f2bf((accq[nt][r] + bq[h]) * 0.125f);
    }
    asm volatile("s_waitcnt lgkmcnt(0)" ::: "memory");
    __builtin_amdgcn_sched_barrier(0);
    qa0 = *reinterpret_cast<const bf16x8*>(&Pw[l15 * 72 + l4 * 8]);
    qa1 = *reinterpret_cast<const bf16x8*>(&Pw[l15 * 72 + 32 + l4 * 8]);
  }

  f32x4 acco[4];
  #pragma unroll
  for (int i = 0; i < 4; ++i) acco[i] = zero4;
  float mrow[4] = {-1e30f, -1e30f, -1e30f, -1e30f};
  float lrow[4] = {0.f, 0.f, 0.f, 0.f};

  const int ktmax = blockIdx.x;
  for (int kt = 0; kt <= ktmax; ++kt) {
    const int kv0 = kt * 64;
    __syncthreads();
    #pragma unroll
    for (int p = 0; p < 2; ++p) {  // stage K and V tiles
      int chunk = tid + p * 256;
      int r = chunk >> 3, c8 = chunk & 7;
      *reinterpret_cast<bf16x8*>(&Kl[r * 72 + c8 * 8]) =
          *reinterpret_cast<const bf16x8*>(Kr + ((size_t)b * 4096 + kv0 + r) * 64 + c8 * 8);
      *reinterpret_cast<bf16x8*>(&Vl[r * 72 + c8 * 8]) =
          *reinterpret_cast<const bf16x8*>(Vt + ((size_t)b * 64 + r) * 4096 + kv0 + c8 * 8);
    }
    __syncthreads();

    f32x4 s[4];
    #pragma unroll
    for (int i = 0; i < 4; ++i) s[i] = zero4;
    #pragma unroll
    for (int nt = 0; nt < 4; ++nt) {
      bf16x8 k0 = *reinterpret_cast<const bf16x8*>(&Kl[(nt * 16 + l15) * 72 + l4 * 8]);
      bf16x8 k1 = *reinterpret_cast<const bf16x8*>(&Kl[(nt * 16 + l15) * 72 + 32 + l4 * 8]);
      s[nt] = __builtin_amdgcn_mfma_f32_16x16x32_bf16(qa0, k0, s[nt], 0, 0, 0);
      s[nt] = __builtin_amdgcn_mfma_f32_16x16x32_bf16(qa1, k1, s[nt], 0, 0, 0);
    }
    if (kt == ktmax) {  // diagonal tile: causal mask
      #pragma unroll
      for (int nt = 0; nt < 4; ++nt) {
        int kv_g = kv0 + nt * 16 + l15;
        #pragma unroll
        for (int r = 0; r < 4; ++r) {
          int q_g = qrow + l4 * 4 + r;
          if (kv_g > q_g) s[nt][r] = -1e30f;
        }
      }
    }
    #pragma unroll
    for (int r = 0; r < 4; ++r) {  // online softmax (row in one 16-lane group)
      float t = fmaxf(fmaxf(s[0][r], s[1][r]), fmaxf(s[2][r], s[3][r]));
      t = fmaxf(t, __shfl_xor(t, 1));
      t = fmaxf(t, __shfl_xor(t, 2));
      t = fmaxf(t, __shfl_xor(t, 4));
      t = fmaxf(t, __shfl_xor(t, 8));
      float mnew = fmaxf(mrow[r], t);
      float cc = __expf(mrow[r] - mnew);
      mrow[r] = mnew;
      lrow[r] *= cc;
      acco[0][r] *= cc; acco[1][r] *= cc; acco[2][r] *= cc; acco[3][r] *= cc;
    }
    #pragma unroll
    for (int nt = 0; nt < 4; ++nt) {
      #pragma unroll
      for (int r = 0; r < 4; ++r) {
        float p = __expf(s[nt][r] - mrow[r]);
        s[nt][r] = p;
        Pw[(l4 * 4 + r) * 72 + nt * 16 + l15] = f2bf(p);
      }
    }
    #pragma unroll
    for (int r = 0; r < 4; ++r) {
      float t = s[0][r] + s[1][r] + s[2][r] + s[3][r];
      t += __shfl_xor(t, 1);
      t += __shfl_xor(t, 2);
      t += __shfl_xor(t, 4);
      t += __shfl_xor(t, 8);
      lrow[r] += t;
    }
    asm volatile("s_waitcnt lgkmcnt(0)" ::: "memory");
    __builtin_amdgcn_sched_barrier(0);
    #pragma unroll
    for (int ks = 0; ks < 2; ++ks) {  // O += P V
      bf16x8 pa = *reinterpret_cast<const bf16x8*>(&Pw[l15 * 72 + ks * 32 + l4 * 8]);
      #pragma unroll
      for (int ht = 0; ht < 4; ++ht) {
        bf16x8 vf = *reinterpret_cast<const bf16x8*>(&Vl[(ht * 16 + l15) * 72 + ks * 32 + l4 * 8]);
        acco[ht] = __builtin_amdgcn_mfma_f32_16x16x32_bf16(pa, vf, acco[ht], 0, 0, 0);
      }
    }
  }
  float* ob = out + ((size_t)b * 4096 + qrow) * 64;
  #pragma unroll
  for (int ht = 0; ht < 4; ++ht) {
    #pragma unroll
    for (int r = 0; r < 4; ++r) {
      ob[(l4 * 4 + r) * 64 + ht * 16 + l15] = acco[ht][r] / lrow[r];
    }
  }
}

extern "C" void kernel_launch(void* const* d_in, const int* in_sizes, int n_in,
                              void* d_out, int out_size, void* d_ws, size_t ws_size,
                              hipStream_t stream) {
  const float* X  = (const float*)d_in[0];
  const float* Wk = (const float*)d_in[1];
  const float* bk = (const float*)d_in[2];
  const float* Wq = (const float*)d_in[3];
  const float* bq = (const float*)d_in[4];
  const float* Wv = (const float*)d_in[5];
  const float* bv = (const float*)d_in[6];
  float* out = (float*)d_out;

  char* ws = (char*)d_ws;
  const size_t SZ = 2097152;  // one bf16 [B*T][64] buffer
  unsigned short* Kr = (unsigned short*)(ws);
  unsigned short* Vt = (unsigned short*)(ws + SZ);

  if (ws_size >= 3 * SZ) {
    unsigned short* Qs = (unsigned short*)(ws + 2 * SZ);
    proj_kernel<true><<<256, 256, 0, stream>>>(X, Wk, Wq, Wv, bk, bq, bv, Kr, Qs, Vt);
    attn_kernel<false><<<dim3(64, 4), 256, 0, stream>>>(Qs, Kr, Vt, X, Wq, bq, out);
  } else {
    proj_kernel<false><<<256, 256, 0, stream>>>(X, Wk, Wq, Wv, bk, bq, bv, Kr, nullptr, Vt);
    attn_kernel<true><<<dim3(64, 4), 256, 0, stream>>>(nullptr, Kr, Vt, X, Wq, bq, out);
  }
}

// Round 4
// 134.520 us; speedup vs baseline: 1.4903x; 1.4903x over previous
//
#include <hip/hip_runtime.h>

// AttentionHead: B=4, T=4096, C=1024, H=64, causal softmax(QK^T/8)V
// R4: attn rewritten — 512 blocks (32 q-rows, 2 waves), longest-first order,
// double-buffered K/V via global_load_lds + XOR swizzle, exp2 softmax, setprio.
// proj unchanged (attribution). Plan A (ws>=6.29MB): Kr|Vt|Qs. Plan B fallback.

using bf16x8 = __attribute__((ext_vector_type(8))) short;
using bf16x4 = __attribute__((ext_vector_type(4))) short;
using f32x4  = __attribute__((ext_vector_type(4))) float;

#define QSCALE 0.1803368867f  // 0.125 * log2(e): softmax done in exp2 domain

__device__ __forceinline__ unsigned short f2bf(float f) {
  union { float f; unsigned int u; } v; v.f = f;
  unsigned int r = v.u + 0x7fffu + ((v.u >> 16) & 1u);  // RNE
  return (unsigned short)(r >> 16);
}

__device__ __forceinline__ float fexp2(float x) {
#if __has_builtin(__builtin_amdgcn_exp2f)
  return __builtin_amdgcn_exp2f(x);
#else
  float r; asm("v_exp_f32 %0, %1" : "=v"(r) : "v"(x)); return r;
#endif
}

__device__ __forceinline__ void gl_lds16(const void* g, void* l) {
  __builtin_amdgcn_global_load_lds(
      (const __attribute__((address_space(1))) void*)g,
      (__attribute__((address_space(3))) void*)l, 16, 0, 0);
}

// ---- projections: 64 rows x (K[,Q],V) cols per block, K=1024 ----------
template <bool WRITE_Q>
__global__ __launch_bounds__(256) void proj_kernel(
    const float* __restrict__ X,  const float* __restrict__ Wk,
    const float* __restrict__ Wq, const float* __restrict__ Wv,
    const float* __restrict__ bk, const float* __restrict__ bq,
    const float* __restrict__ bv, unsigned short* __restrict__ Kr,
    unsigned short* __restrict__ Qs, unsigned short* __restrict__ Vt) {
  constexpr int NT = WRITE_Q ? 12 : 8;
  constexpr int NC = NT / 4;
  __shared__ __align__(16) unsigned short Xl[64 * 72];
  __shared__ __align__(16) unsigned short Wl[NT * 16 * 72];
  const int tid = threadIdx.x;
  const int m0  = blockIdx.x * 64;
  const int w   = tid >> 6;
  const int ln  = tid & 63;
  const int l15 = ln & 15;
  const int l4  = ln >> 4;
  const f32x4 zero4 = {0.f, 0.f, 0.f, 0.f};

  f32x4 acc[NT];
  #pragma unroll
  for (int i = 0; i < NT; ++i) acc[i] = zero4;

  const int wn = tid & 63;
  const int wk = (tid >> 6) * 16;

  for (int kb = 0; kb < 16; ++kb) {
    __syncthreads();
    #pragma unroll
    for (int p = 0; p < 4; ++p) {
      int chunk = tid + p * 256;
      int r = chunk >> 4, c4 = chunk & 15;
      const float4 xv = *reinterpret_cast<const float4*>(
          X + (size_t)(m0 + r) * 1024 + kb * 64 + c4 * 4);
      bf16x4 o;
      o[0] = (short)f2bf(xv.x); o[1] = (short)f2bf(xv.y);
      o[2] = (short)f2bf(xv.z); o[3] = (short)f2bf(xv.w);
      *reinterpret_cast<bf16x4*>(&Xl[r * 72 + c4 * 4]) = o;
    }
    #pragma unroll
    for (int c = 0; c < NC; ++c) {
      const float* Wsrc = (c == 0) ? Wk : ((WRITE_Q && c == 1) ? Wq : Wv);
      bf16x8 w0, w1;
      #pragma unroll
      for (int j = 0; j < 8; ++j)
        w0[j] = (short)f2bf(Wsrc[(size_t)(kb * 64 + wk + j) * 64 + wn]);
      #pragma unroll
      for (int j = 0; j < 8; ++j)
        w1[j] = (short)f2bf(Wsrc[(size_t)(kb * 64 + wk + 8 + j) * 64 + wn]);
      *reinterpret_cast<bf16x8*>(&Wl[(c * 64 + wn) * 72 + wk])     = w0;
      *reinterpret_cast<bf16x8*>(&Wl[(c * 64 + wn) * 72 + wk + 8]) = w1;
    }
    __syncthreads();
    bf16x8 a0 = *reinterpret_cast<const bf16x8*>(&Xl[(w * 16 + l15) * 72 + l4 * 8]);
    bf16x8 a1 = *reinterpret_cast<const bf16x8*>(&Xl[(w * 16 + l15) * 72 + 32 + l4 * 8]);
    #pragma unroll
    for (int nt = 0; nt < NT; ++nt) {
      bf16x8 b0 = *reinterpret_cast<const bf16x8*>(&Wl[(nt * 16 + l15) * 72 + l4 * 8]);
      bf16x8 b1 = *reinterpret_cast<const bf16x8*>(&Wl[(nt * 16 + l15) * 72 + 32 + l4 * 8]);
      acc[nt] = __builtin_amdgcn_mfma_f32_16x16x32_bf16(a0, b0, acc[nt], 0, 0, 0);
      acc[nt] = __builtin_amdgcn_mfma_f32_16x16x32_bf16(a1, b1, acc[nt], 0, 0, 0);
    }
  }
  #pragma unroll
  for (int nt = 0; nt < NT; ++nt) {
    int j = nt * 16 + l15;
    #pragma unroll
    for (int r = 0; r < 4; ++r) {
      int m = m0 + w * 16 + l4 * 4 + r;
      float v = acc[nt][r];
      if (nt < 4) {
        Kr[(size_t)m * 64 + j] = f2bf(v + bk[j]);
      } else if (WRITE_Q && nt < 8) {
        Qs[(size_t)m * 64 + (j - 64)] = f2bf((v + bq[j - 64]) * QSCALE);
      } else {
        int h = j - (WRITE_Q ? 128 : 64);
        int bb = m >> 12, t = m & 4095;
        Vt[((size_t)(bb * 64 + h)) * 4096 + t] = f2bf(v + bv[h]);
      }
    }
  }
}

// ---- attn v2: 512 blocks, 32 q-rows / 2 waves each, dbuf gll staging --
__global__ __launch_bounds__(128) void attn2_kernel(
    const unsigned short* __restrict__ Qs,
    const unsigned short* __restrict__ Kr,
    const unsigned short* __restrict__ Vt,
    float* __restrict__ out) {
  __shared__ __align__(16) unsigned short Kl[2][64 * 64];   // linear, swizzled
  __shared__ __align__(16) unsigned short Vl[2][64 * 64];   // linear, swizzled
  __shared__ __align__(16) unsigned short Pl[2][16 * 72];   // per-wave, padded
  const int tid = threadIdx.x;
  const int w   = tid >> 6;          // 0..1
  const int ln  = tid & 63;
  const int l15 = ln & 15;
  const int l4  = ln >> 4;
  const int bid = blockIdx.x;        // 0..511
  const int qt  = 127 - (bid >> 2);  // longest-first dispatch
  const int b   = bid & 3;           // batch; bid%8 pins batch pairs per XCD
  const int q0  = qt * 32;
  const int qrow = q0 + w * 16;
  const int ntiles = (qt >> 1) + 1;  // kv tiles of 64 needed
  const f32x4 zero4 = {0.f, 0.f, 0.f, 0.f};
  unsigned short* Pw = &Pl[w][0];

  // lane-constant swizzled source offsets (granule g -> g ^ ((g>>3)&7))
  const int lswz16 = (ln ^ (ln >> 3)) * 16;              // K: byte off per lane
  const int vrow_l = ln >> 3;                            // V: row part
  const int vcol_l = ((ln & 7) ^ (ln >> 3)) * 16;        // V: col byte part
  const char* Kbase = (const char*)Kr + (size_t)b * 4096 * 128;
  const char* Vbase = (const char*)Vt + (size_t)b * 64 * 8192;

  auto stage = [&](int buf, int kt) {
    if (w == 0) {
      const char* src = Kbase + (size_t)kt * 8192 + lswz16;
      #pragma unroll
      for (int j = 0; j < 8; ++j)
        gl_lds16(src + j * 1024, (char*)&Kl[buf][0] + j * 1024);
    } else {
      const char* src = Vbase + (size_t)kt * 128 + (size_t)vrow_l * 8192 + vcol_l;
      #pragma unroll
      for (int j = 0; j < 8; ++j)
        gl_lds16(src + (size_t)j * 8 * 8192, (char*)&Vl[buf][0] + j * 1024);
    }
  };

  const unsigned short* Qbase = Qs + ((size_t)b * 4096 + qrow + l15) * 64;
  const bf16x8 qa0 = *reinterpret_cast<const bf16x8*>(Qbase + l4 * 8);
  const bf16x8 qa1 = *reinterpret_cast<const bf16x8*>(Qbase + 32 + l4 * 8);

  f32x4 acco[4];
  #pragma unroll
  for (int i = 0; i < 4; ++i) acco[i] = zero4;
  float mrow[4] = {-1e30f, -1e30f, -1e30f, -1e30f};
  float lrow[4] = {0.f, 0.f, 0.f, 0.f};

  int cur = 0;
  stage(0, 0);
  asm volatile("s_waitcnt vmcnt(0)" ::: "memory");
  __syncthreads();

  for (int kt = 0; kt < ntiles; ++kt) {
    const bool last = (kt == ntiles - 1);
    if (!last) stage(cur ^ 1, kt + 1);   // prefetch next tile (flies over compute)

    // ---- S = Q K^T (log2 domain, Q pre-scaled)
    f32x4 s[4];
    #pragma unroll
    for (int i = 0; i < 4; ++i) s[i] = zero4;
    __builtin_amdgcn_s_setprio(1);
    #pragma unroll
    for (int nt = 0; nt < 4; ++nt) {
      const int krow = nt * 16 + l15;
      const unsigned short* kp = &Kl[cur][krow * 64];
      bf16x8 k0 = *reinterpret_cast<const bf16x8*>(kp + ((l4 ^ (krow & 7)) << 3));
      bf16x8 k1 = *reinterpret_cast<const bf16x8*>(kp + (((l4 + 4) ^ (krow & 7)) << 3));
      s[nt] = __builtin_amdgcn_mfma_f32_16x16x32_bf16(qa0, k0, s[nt], 0, 0, 0);
      s[nt] = __builtin_amdgcn_mfma_f32_16x16x32_bf16(qa1, k1, s[nt], 0, 0, 0);
    }
    __builtin_amdgcn_s_setprio(0);

    if (last) {  // causal mask (only the last tile can cross the diagonal)
      #pragma unroll
      for (int nt = 0; nt < 4; ++nt) {
        int kv_g = kt * 64 + nt * 16 + l15;
        #pragma unroll
        for (int r = 0; r < 4; ++r) {
          int q_g = qrow + l4 * 4 + r;
          if (kv_g > q_g) s[nt][r] = -1e30f;
        }
      }
    }
    // ---- online softmax (row lives in one 16-lane group), exp2 domain
    #pragma unroll
    for (int r = 0; r < 4; ++r) {
      float t = fmaxf(fmaxf(s[0][r], s[1][r]), fmaxf(s[2][r], s[3][r]));
      t = fmaxf(t, __shfl_xor(t, 1));
      t = fmaxf(t, __shfl_xor(t, 2));
      t = fmaxf(t, __shfl_xor(t, 4));
      t = fmaxf(t, __shfl_xor(t, 8));
      float mnew = fmaxf(mrow[r], t);
      float cc = fexp2(mrow[r] - mnew);
      mrow[r] = mnew;
      lrow[r] *= cc;
      acco[0][r] *= cc; acco[1][r] *= cc; acco[2][r] *= cc; acco[3][r] *= cc;
    }
    #pragma unroll
    for (int nt = 0; nt < 4; ++nt) {
      #pragma unroll
      for (int r = 0; r < 4; ++r) {
        float p = fexp2(s[nt][r] - mrow[r]);
        s[nt][r] = p;
        Pw[(l4 * 4 + r) * 72 + nt * 16 + l15] = f2bf(p);
      }
    }
    #pragma unroll
    for (int r = 0; r < 4; ++r) {
      float t = s[0][r] + s[1][r] + s[2][r] + s[3][r];
      t += __shfl_xor(t, 1);
      t += __shfl_xor(t, 2);
      t += __shfl_xor(t, 4);
      t += __shfl_xor(t, 8);
      lrow[r] += t;
    }
    asm volatile("s_waitcnt lgkmcnt(0)" ::: "memory");
    __builtin_amdgcn_sched_barrier(0);
    // ---- O += P V
    #pragma unroll
    for (int ks = 0; ks < 2; ++ks) {
      bf16x8 pa = *reinterpret_cast<const bf16x8*>(&Pw[l15 * 72 + ks * 32 + l4 * 8]);
      __builtin_amdgcn_s_setprio(1);
      #pragma unroll
      for (int ht = 0; ht < 4; ++ht) {
        const int vrow = ht * 16 + l15;
        const unsigned short* vp = &Vl[cur][vrow * 64];
        bf16x8 vf = *reinterpret_cast<const bf16x8*>(
            vp + (((ks * 4 + l4) ^ (vrow & 7)) << 3));
        acco[ht] = __builtin_amdgcn_mfma_f32_16x16x32_bf16(pa, vf, acco[ht], 0, 0, 0);
      }
      __builtin_amdgcn_s_setprio(0);
    }

    if (!last) {
      asm volatile("s_waitcnt vmcnt(0)" ::: "memory");  // next tile landed
      __syncthreads();
      cur ^= 1;
    }
  }

  float* ob = out + ((size_t)b * 4096 + qrow) * 64;
  #pragma unroll
  for (int ht = 0; ht < 4; ++ht) {
    #pragma unroll
    for (int r = 0; r < 4; ++r) {
      ob[(l4 * 4 + r) * 64 + ht * 16 + l15] = acco[ht][r] / lrow[r];
    }
  }
}

// ---- Plan-B fallback attn (recomputes Q; original slow version) -------
__global__ __launch_bounds__(256) void attnB_kernel(
    const unsigned short* __restrict__ Kr,
    const unsigned short* __restrict__ Vt,
    const float* __restrict__ X, const float* __restrict__ Wq,
    const float* __restrict__ bq, float* __restrict__ out) {
  __shared__ __align__(16) unsigned short Kl[64 * 72];
  __shared__ __align__(16) unsigned short Vl[64 * 72];
  __shared__ __align__(16) unsigned short Pl[4 * 16 * 72];
  const int tid = threadIdx.x;
  const int w   = tid >> 6;
  const int ln  = tid & 63;
  const int l15 = ln & 15;
  const int l4  = ln >> 4;
  const int b   = blockIdx.y;
  const int q0  = blockIdx.x * 64;
  const int qrow = q0 + w * 16;
  const f32x4 zero4 = {0.f, 0.f, 0.f, 0.f};
  unsigned short* Pw = &Pl[w * 16 * 72];

  f32x4 accq[4];
  #pragma unroll
  for (int i = 0; i < 4; ++i) accq[i] = zero4;
  const int wn = tid & 63;
  const int wk = (tid >> 6) * 16;
  for (int kb = 0; kb < 16; ++kb) {
    __syncthreads();
    #pragma unroll
    for (int p = 0; p < 4; ++p) {
      int chunk = tid + p * 256;
      int r = chunk >> 4, c4 = chunk & 15;
      const float4 xv = *reinterpret_cast<const float4*>(
          X + ((size_t)b * 4096 + q0 + r) * 1024 + kb * 64 + c4 * 4);
      bf16x4 o;
      o[0] = (short)f2bf(xv.x); o[1] = (short)f2bf(xv.y);
      o[2] = (short)f2bf(xv.z); o[3] = (short)f2bf(xv.w);
      *reinterpret_cast<bf16x4*>(&Kl[r * 72 + c4 * 4]) = o;
    }
    bf16x8 w0, w1;
    #pragma unroll
    for (int j = 0; j < 8; ++j)
      w0[j] = (short)f2bf(Wq[(size_t)(kb * 64 + wk + j) * 64 + wn]);
    #pragma unroll
    for (int j = 0; j < 8; ++j)
      w1[j] = (short)f2bf(Wq[(size_t)(kb * 64 + wk + 8 + j) * 64 + wn]);
    *reinterpret_cast<bf16x8*>(&Vl[wn * 72 + wk])     = w0;
    *reinterpret_cast<bf16x8*>(&Vl[wn * 72 + wk + 8]) = w1;
    __syncthreads();
    bf16x8 a0 = *reinterpret_cast<const bf16x8*>(&Kl[(w * 16 + l15) * 72 + l4 * 8]);
    bf16x8 a1 = *reinterpret_cast<const bf16x8*>(&Kl[(w * 16 + l15) * 72 + 32 + l4 * 8]);
    #pragma unroll
    for (int nt = 0; nt < 4; ++nt) {
      bf16x8 b0 = *reinterpret_cast<const bf16x8*>(&Vl[(nt * 16 + l15) * 72 + l4 * 8]);
      bf16x8 b1 = *reinterpret_cast<const bf16x8*>(&Vl[(nt * 16 + l15) * 72 + 32 + l4 * 8]);
      accq[nt] = __builtin_amdgcn_mfma_f32_16x16x32_bf16(a0, b0, accq[nt], 0, 0, 0);
      accq[nt] = __builtin_amdgcn_mfma_f32_16x16x32_bf16(a1, b1, accq[nt], 0, 0, 0);
    }
  }
  #pragma unroll
  for (int nt = 0; nt < 4; ++nt) {
    int h = nt * 16 + l15;
    #pragma unroll
    for (int r = 0; r < 4; ++r)
      Pw[(l4 * 4 + r) * 72 + h] = f2bf((accq[nt][r] + bq[h]) * 0.125f);
  }
  asm volatile("s_waitcnt lgkmcnt(0)" ::: "memory");
  __builtin_amdgcn_sched_barrier(0);
  bf16x8 qa0 = *reinterpret_cast<const bf16x8*>(&Pw[l15 * 72 + l4 * 8]);
  bf16x8 qa1 = *reinterpret_cast<const bf16x8*>(&Pw[l15 * 72 + 32 + l4 * 8]);

  f32x4 acco[4];
  #pragma unroll
  for (int i = 0; i < 4; ++i) acco[i] = zero4;
  float mrow[4] = {-1e30f, -1e30f, -1e30f, -1e30f};
  float lrow[4] = {0.f, 0.f, 0.f, 0.f};

  const int ktmax = blockIdx.x;
  for (int kt = 0; kt <= ktmax; ++kt) {
    const int kv0 = kt * 64;
    __syncthreads();
    #pragma unroll
    for (int p = 0; p < 2; ++p) {
      int chunk = tid + p * 256;
      int r = chunk >> 3, c8 = chunk & 7;
      *reinterpret_cast<bf16x8*>(&Kl[r * 72 + c8 * 8]) =
          *reinterpret_cast<const bf16x8*>(Kr + ((size_t)b * 4096 + kv0 + r) * 64 + c8 * 8);
      *reinterpret_cast<bf16x8*>(&Vl[r * 72 + c8 * 8]) =
          *reinterpret_cast<const bf16x8*>(Vt + ((size_t)b * 64 + r) * 4096 + kv0 + c8 * 8);
    }
    __syncthreads();
    f32x4 s[4];
    #pragma unroll
    for (int i = 0; i < 4; ++i) s[i] = zero4;
    #pragma unroll
    for (int nt = 0; nt < 4; ++nt) {
      bf16x8 k0 = *reinterpret_cast<const bf16x8*>(&Kl[(nt * 16 + l15) * 72 + l4 * 8]);
      bf16x8 k1 = *reinterpret_cast<const bf16x8*>(&Kl[(nt * 16 + l15) * 72 + 32 + l4 * 8]);
      s[nt] = __builtin_amdgcn_mfma_f32_16x16x32_bf16(qa0, k0, s[nt], 0, 0, 0);
      s[nt] = __builtin_amdgcn_mfma_f32_16x16x32_bf16(qa1, k1, s[nt], 0, 0, 0);
    }
    if (kt == ktmax) {
      #pragma unroll
      for (int nt = 0; nt < 4; ++nt) {
        int kv_g = kv0 + nt * 16 + l15;
        #pragma unroll
        for (int r = 0; r < 4; ++r) {
          int q_g = qrow + l4 * 4 + r;
          if (kv_g > q_g) s[nt][r] = -1e30f;
        }
      }
    }
    #pragma unroll
    for (int r = 0; r < 4; ++r) {
      float t = fmaxf(fmaxf(s[0][r], s[1][r]), fmaxf(s[2][r], s[3][r]));
      t = fmaxf(t, __shfl_xor(t, 1));
      t = fmaxf(t, __shfl_xor(t, 2));
      t = fmaxf(t, __shfl_xor(t, 4));
      t = fmaxf(t, __shfl_xor(t, 8));
      float mnew = fmaxf(mrow[r], t);
      float cc = __expf(mrow[r] - mnew);
      mrow[r] = mnew;
      lrow[r] *= cc;
      acco[0][r] *= cc; acco[1][r] *= cc; acco[2][r] *= cc; acco[3][r] *= cc;
    }
    #pragma unroll
    for (int nt = 0; nt < 4; ++nt) {
      #pragma unroll
      for (int r = 0; r < 4; ++r) {
        float p = __expf(s[nt][r] - mrow[r]);
        s[nt][r] = p;
        Pw[(l4 * 4 + r) * 72 + nt * 16 + l15] = f2bf(p);
      }
    }
    #pragma unroll
    for (int r = 0; r < 4; ++r) {
      float t = s[0][r] + s[1][r] + s[2][r] + s[3][r];
      t += __shfl_xor(t, 1);
      t += __shfl_xor(t, 2);
      t += __shfl_xor(t, 4);
      t += __shfl_xor(t, 8);
      lrow[r] += t;
    }
    asm volatile("s_waitcnt lgkmcnt(0)" ::: "memory");
    __builtin_amdgcn_sched_barrier(0);
    #pragma unroll
    for (int ks = 0; ks < 2; ++ks) {
      bf16x8 pa = *reinterpret_cast<const bf16x8*>(&Pw[l15 * 72 + ks * 32 + l4 * 8]);
      #pragma unroll
      for (int ht = 0; ht < 4; ++ht) {
        bf16x8 vf = *reinterpret_cast<const bf16x8*>(&Vl[(ht * 16 + l15) * 72 + ks * 32 + l4 * 8]);
        acco[ht] = __builtin_amdgcn_mfma_f32_16x16x32_bf16(pa, vf, acco[ht], 0, 0, 0);
      }
    }
  }
  float* ob = out + ((size_t)b * 4096 + qrow) * 64;
  #pragma unroll
  for (int ht = 0; ht < 4; ++ht) {
    #pragma unroll
    for (int r = 0; r < 4; ++r) {
      ob[(l4 * 4 + r) * 64 + ht * 16 + l15] = acco[ht][r] / lrow[r];
    }
  }
}

extern "C" void kernel_launch(void* const* d_in, const int* in_sizes, int n_in,
                              void* d_out, int out_size, void* d_ws, size_t ws_size,
                              hipStream_t stream) {
  const float* X  = (const float*)d_in[0];
  const float* Wk = (const float*)d_in[1];
  const float* bk = (const float*)d_in[2];
  const float* Wq = (const float*)d_in[3];
  const float* bq = (const float*)d_in[4];
  const float* Wv = (const float*)d_in[5];
  const float* bv = (const float*)d_in[6];
  float* out = (float*)d_out;

  char* ws = (char*)d_ws;
  const size_t SZ = 2097152;  // one bf16 [B*T][64] buffer
  unsigned short* Kr = (unsigned short*)(ws);
  unsigned short* Vt = (unsigned short*)(ws + SZ);

  if (ws_size >= 3 * SZ) {
    unsigned short* Qs = (unsigned short*)(ws + 2 * SZ);
    proj_kernel<true><<<256, 256, 0, stream>>>(X, Wk, Wq, Wv, bk, bq, bv, Kr, Qs, Vt);
    attn2_kernel<<<512, 128, 0, stream>>>(Qs, Kr, Vt, out);
  } else {
    proj_kernel<false><<<256, 256, 0, stream>>>(X, Wk, Wq, Wv, bk, bq, bv, Kr, nullptr, Vt);
    attnB_kernel<<<dim3(64, 4), 256, 0, stream>>>(Kr, Vt, X, Wq, bq, out);
  }
}

// Round 5
// 99.639 us; speedup vs baseline: 2.0120x; 1.3501x over previous
//
#include <hip/hip_runtime.h>

// AttentionHead: B=4, T=4096, C=1024, H=64, causal softmax(QK^T/8)V
// R5: attn = 512 blocks x 4 waves; kv-parity split inside block (2 pairs,
// each pair = private online-softmax state + private dbuf gll K/V pipeline),
// exact fp32 merge at end via LDS. 8 waves/CU (2/SIMD). proj unchanged.

using bf16x8 = __attribute__((ext_vector_type(8))) short;
using bf16x4 = __attribute__((ext_vector_type(4))) short;
using f32x4  = __attribute__((ext_vector_type(4))) float;

#define QSCALE 0.1803368867f  // 0.125 * log2(e): softmax in exp2 domain

__device__ __forceinline__ unsigned short f2bf(float f) {
  union { float f; unsigned int u; } v; v.f = f;
  unsigned int r = v.u + 0x7fffu + ((v.u >> 16) & 1u);  // RNE
  return (unsigned short)(r >> 16);
}

__device__ __forceinline__ float fexp2(float x) {
#if __has_builtin(__builtin_amdgcn_exp2f)
  return __builtin_amdgcn_exp2f(x);
#else
  float r; asm("v_exp_f32 %0, %1" : "=v"(r) : "v"(x)); return r;
#endif
}

__device__ __forceinline__ void gl_lds16(const void* g, void* l) {
  __builtin_amdgcn_global_load_lds(
      (const __attribute__((address_space(1))) void*)g,
      (__attribute__((address_space(3))) void*)l, 16, 0, 0);
}

// ---- projections: 64 rows x (K[,Q],V) cols per block, K=1024 ----------
template <bool WRITE_Q>
__global__ __launch_bounds__(256) void proj_kernel(
    const float* __restrict__ X,  const float* __restrict__ Wk,
    const float* __restrict__ Wq, const float* __restrict__ Wv,
    const float* __restrict__ bk, const float* __restrict__ bq,
    const float* __restrict__ bv, unsigned short* __restrict__ Kr,
    unsigned short* __restrict__ Qs, unsigned short* __restrict__ Vt) {
  constexpr int NT = WRITE_Q ? 12 : 8;
  constexpr int NC = NT / 4;
  __shared__ __align__(16) unsigned short Xl[64 * 72];
  __shared__ __align__(16) unsigned short Wl[NT * 16 * 72];
  const int tid = threadIdx.x;
  const int m0  = blockIdx.x * 64;
  const int w   = tid >> 6;
  const int ln  = tid & 63;
  const int l15 = ln & 15;
  const int l4  = ln >> 4;
  const f32x4 zero4 = {0.f, 0.f, 0.f, 0.f};

  f32x4 acc[NT];
  #pragma unroll
  for (int i = 0; i < NT; ++i) acc[i] = zero4;

  const int wn = tid & 63;
  const int wk = (tid >> 6) * 16;

  for (int kb = 0; kb < 16; ++kb) {
    __syncthreads();
    #pragma unroll
    for (int p = 0; p < 4; ++p) {
      int chunk = tid + p * 256;
      int r = chunk >> 4, c4 = chunk & 15;
      const float4 xv = *reinterpret_cast<const float4*>(
          X + (size_t)(m0 + r) * 1024 + kb * 64 + c4 * 4);
      bf16x4 o;
      o[0] = (short)f2bf(xv.x); o[1] = (short)f2bf(xv.y);
      o[2] = (short)f2bf(xv.z); o[3] = (short)f2bf(xv.w);
      *reinterpret_cast<bf16x4*>(&Xl[r * 72 + c4 * 4]) = o;
    }
    #pragma unroll
    for (int c = 0; c < NC; ++c) {
      const float* Wsrc = (c == 0) ? Wk : ((WRITE_Q && c == 1) ? Wq : Wv);
      bf16x8 w0, w1;
      #pragma unroll
      for (int j = 0; j < 8; ++j)
        w0[j] = (short)f2bf(Wsrc[(size_t)(kb * 64 + wk + j) * 64 + wn]);
      #pragma unroll
      for (int j = 0; j < 8; ++j)
        w1[j] = (short)f2bf(Wsrc[(size_t)(kb * 64 + wk + 8 + j) * 64 + wn]);
      *reinterpret_cast<bf16x8*>(&Wl[(c * 64 + wn) * 72 + wk])     = w0;
      *reinterpret_cast<bf16x8*>(&Wl[(c * 64 + wn) * 72 + wk + 8]) = w1;
    }
    __syncthreads();
    bf16x8 a0 = *reinterpret_cast<const bf16x8*>(&Xl[(w * 16 + l15) * 72 + l4 * 8]);
    bf16x8 a1 = *reinterpret_cast<const bf16x8*>(&Xl[(w * 16 + l15) * 72 + 32 + l4 * 8]);
    #pragma unroll
    for (int nt = 0; nt < NT; ++nt) {
      bf16x8 b0 = *reinterpret_cast<const bf16x8*>(&Wl[(nt * 16 + l15) * 72 + l4 * 8]);
      bf16x8 b1 = *reinterpret_cast<const bf16x8*>(&Wl[(nt * 16 + l15) * 72 + 32 + l4 * 8]);
      acc[nt] = __builtin_amdgcn_mfma_f32_16x16x32_bf16(a0, b0, acc[nt], 0, 0, 0);
      acc[nt] = __builtin_amdgcn_mfma_f32_16x16x32_bf16(a1, b1, acc[nt], 0, 0, 0);
    }
  }
  #pragma unroll
  for (int nt = 0; nt < NT; ++nt) {
    int j = nt * 16 + l15;
    #pragma unroll
    for (int r = 0; r < 4; ++r) {
      int m = m0 + w * 16 + l4 * 4 + r;
      float v = acc[nt][r];
      if (nt < 4) {
        Kr[(size_t)m * 64 + j] = f2bf(v + bk[j]);
      } else if (WRITE_Q && nt < 8) {
        Qs[(size_t)m * 64 + (j - 64)] = f2bf((v + bq[j - 64]) * QSCALE);
      } else {
        int h = j - (WRITE_Q ? 128 : 64);
        int bb = m >> 12, t = m & 4095;
        Vt[((size_t)(bb * 64 + h)) * 4096 + t] = f2bf(v + bv[h]);
      }
    }
  }
}

// ---- attn v3: 512 blocks, 4 waves = 2 kv-parity pairs x 16 q-rows -----
__global__ __launch_bounds__(256) void attn3_kernel(
    const unsigned short* __restrict__ Qs,
    const unsigned short* __restrict__ Kr,
    const unsigned short* __restrict__ Vt,
    float* __restrict__ out) {
  __shared__ __align__(16) unsigned short Kl[2][2][64 * 64];  // [pair][buf]
  __shared__ __align__(16) unsigned short Vl[2][2][64 * 64];
  __shared__ __align__(16) unsigned short Pl[4][16 * 72];
  const int tid = threadIdx.x;
  const int w    = tid >> 6;         // 0..3
  const int pair = w >> 1;           // 0 = even kv tiles, 1 = odd
  const int qh   = w & 1;            // q half (rows 0-15 / 16-31)
  const int ln  = tid & 63;
  const int l15 = ln & 15;
  const int l4  = ln >> 4;
  const int bid = blockIdx.x;        // 0..511
  const int qt  = 127 - (bid >> 2);  // longest-first
  const int b   = bid & 3;
  const int q0  = qt * 32;
  const int qrow = q0 + qh * 16;
  const int ntiles = (qt >> 1) + 1;  // kv tiles of 64
  const int ITER = (ntiles + 1) >> 1;
  const f32x4 zero4 = {0.f, 0.f, 0.f, 0.f};
  unsigned short* Pw = &Pl[w][0];

  // swizzled per-lane source offsets (granule g -> g ^ (g>>3), rule #21)
  const int lswz16 = (ln ^ (ln >> 3)) * 16;
  const int vrow_l = ln >> 3;
  const int vcol_l = ((ln & 7) ^ (ln >> 3)) * 16;
  const char* Kbase = (const char*)Kr + (size_t)b * 4096 * 128;
  const char* Vbase = (const char*)Vt + (size_t)b * 64 * 8192;

  auto stage = [&](int buf, int t) {
    if (qh == 0) {  // lower wave of pair stages K
      const char* src = Kbase + (size_t)t * 8192 + lswz16;
      #pragma unroll
      for (int j = 0; j < 8; ++j)
        gl_lds16(src + j * 1024, (char*)&Kl[pair][buf][0] + j * 1024);
    } else {        // upper wave stages V
      const char* src = Vbase + (size_t)t * 128 + (size_t)vrow_l * 8192 + vcol_l;
      #pragma unroll
      for (int j = 0; j < 8; ++j)
        gl_lds16(src + (size_t)j * 8 * 8192, (char*)&Vl[pair][buf][0] + j * 1024);
    }
  };

  const unsigned short* Qbase = Qs + ((size_t)b * 4096 + qrow + l15) * 64;
  const bf16x8 qa0 = *reinterpret_cast<const bf16x8*>(Qbase + l4 * 8);
  const bf16x8 qa1 = *reinterpret_cast<const bf16x8*>(Qbase + 32 + l4 * 8);

  f32x4 acco[4];
  #pragma unroll
  for (int i = 0; i < 4; ++i) acco[i] = zero4;
  float mrow[4] = {-1e30f, -1e30f, -1e30f, -1e30f};
  float lrow[4] = {0.f, 0.f, 0.f, 0.f};

  int cur = 0;
  if (pair < ntiles) stage(0, pair);   // pair B of qt=0 has no tiles
  asm volatile("s_waitcnt vmcnt(0)" ::: "memory");
  __syncthreads();

  for (int it = 0; it < ITER; ++it) {
    const int t  = 2 * it + pair;
    const int tn = t + 2;
    if (tn < ntiles) stage(cur ^ 1, tn);

    if (t < ntiles) {
      // ---- S = Q K^T
      f32x4 s[4];
      #pragma unroll
      for (int i = 0; i < 4; ++i) s[i] = zero4;
      __builtin_amdgcn_s_setprio(1);
      #pragma unroll
      for (int nt = 0; nt < 4; ++nt) {
        const int krow = nt * 16 + l15;
        const unsigned short* kp = &Kl[pair][cur][krow * 64];
        bf16x8 k0 = *reinterpret_cast<const bf16x8*>(kp + ((l4 ^ (krow & 7)) << 3));
        bf16x8 k1 = *reinterpret_cast<const bf16x8*>(kp + (((l4 + 4) ^ (krow & 7)) << 3));
        s[nt] = __builtin_amdgcn_mfma_f32_16x16x32_bf16(qa0, k0, s[nt], 0, 0, 0);
        s[nt] = __builtin_amdgcn_mfma_f32_16x16x32_bf16(qa1, k1, s[nt], 0, 0, 0);
      }
      __builtin_amdgcn_s_setprio(0);

      if (t == ntiles - 1) {  // only the global last tile crosses the diagonal
        #pragma unroll
        for (int nt = 0; nt < 4; ++nt) {
          int kv_g = t * 64 + nt * 16 + l15;
          #pragma unroll
          for (int r = 0; r < 4; ++r) {
            int q_g = qrow + l4 * 4 + r;
            if (kv_g > q_g) s[nt][r] = -1e30f;
          }
        }
      }
      // ---- online softmax (exp2 domain)
      #pragma unroll
      for (int r = 0; r < 4; ++r) {
        float tmx = fmaxf(fmaxf(s[0][r], s[1][r]), fmaxf(s[2][r], s[3][r]));
        tmx = fmaxf(tmx, __shfl_xor(tmx, 1));
        tmx = fmaxf(tmx, __shfl_xor(tmx, 2));
        tmx = fmaxf(tmx, __shfl_xor(tmx, 4));
        tmx = fmaxf(tmx, __shfl_xor(tmx, 8));
        float mnew = fmaxf(mrow[r], tmx);
        float cc = fexp2(mrow[r] - mnew);
        mrow[r] = mnew;
        lrow[r] *= cc;
        acco[0][r] *= cc; acco[1][r] *= cc; acco[2][r] *= cc; acco[3][r] *= cc;
      }
      #pragma unroll
      for (int nt = 0; nt < 4; ++nt) {
        #pragma unroll
        for (int r = 0; r < 4; ++r) {
          float p = fexp2(s[nt][r] - mrow[r]);
          s[nt][r] = p;
          Pw[(l4 * 4 + r) * 72 + nt * 16 + l15] = f2bf(p);
        }
      }
      #pragma unroll
      for (int r = 0; r < 4; ++r) {
        float ts = s[0][r] + s[1][r] + s[2][r] + s[3][r];
        ts += __shfl_xor(ts, 1);
        ts += __shfl_xor(ts, 2);
        ts += __shfl_xor(ts, 4);
        ts += __shfl_xor(ts, 8);
        lrow[r] += ts;
      }
      asm volatile("s_waitcnt lgkmcnt(0)" ::: "memory");
      __builtin_amdgcn_sched_barrier(0);
      // ---- O += P V
      #pragma unroll
      for (int ks = 0; ks < 2; ++ks) {
        bf16x8 pa = *reinterpret_cast<const bf16x8*>(&Pw[l15 * 72 + ks * 32 + l4 * 8]);
        __builtin_amdgcn_s_setprio(1);
        #pragma unroll
        for (int ht = 0; ht < 4; ++ht) {
          const int vrow = ht * 16 + l15;
          const unsigned short* vp = &Vl[pair][cur][vrow * 64];
          bf16x8 vf = *reinterpret_cast<const bf16x8*>(
              vp + (((ks * 4 + l4) ^ (vrow & 7)) << 3));
          acco[ht] = __builtin_amdgcn_mfma_f32_16x16x32_bf16(pa, vf, acco[ht], 0, 0, 0);
        }
        __builtin_amdgcn_s_setprio(0);
      }
    }

    if (it + 1 < ITER) {
      asm volatile("s_waitcnt vmcnt(0)" ::: "memory");
      __syncthreads();
      cur ^= 1;
    }
  }

  // ---- merge pair B into pair A (exact, fp32), via pair-1 staging LDS --
  __syncthreads();  // everyone done computing/staging
  float* CO = (float*)&Kl[1][qh][0];        // [16][64] f32 per q-half
  float* Cm = (float*)&Vl[1][0][0];         // 32 floats
  float* Cl = (float*)&Vl[1][0][64];        // 32 floats
  if (pair == 1) {
    #pragma unroll
    for (int ht = 0; ht < 4; ++ht)
      #pragma unroll
      for (int r = 0; r < 4; ++r)
        CO[(l4 * 4 + r) * 64 + ht * 16 + l15] = acco[ht][r];
    if (l15 == 0) {
      #pragma unroll
      for (int r = 0; r < 4; ++r) {
        Cm[qh * 16 + l4 * 4 + r] = mrow[r];
        Cl[qh * 16 + l4 * 4 + r] = lrow[r];
      }
    }
  }
  __syncthreads();
  if (pair == 0) {
    float* ob = out + ((size_t)b * 4096 + qrow) * 64;
    #pragma unroll
    for (int r = 0; r < 4; ++r) {
      int lr = l4 * 4 + r;
      float mB = Cm[qh * 16 + lr], lB = Cl[qh * 16 + lr];
      float mM = fmaxf(mrow[r], mB);
      float aA = fexp2(mrow[r] - mM);
      float aB = fexp2(mB - mM);
      float linv = 1.0f / (lrow[r] * aA + lB * aB);
      #pragma unroll
      for (int ht = 0; ht < 4; ++ht) {
        float oB = CO[lr * 64 + ht * 16 + l15];
        ob[lr * 64 + ht * 16 + l15] = (acco[ht][r] * aA + oB * aB) * linv;
      }
    }
  }
}

// ---- Plan-B fallback attn (recomputes Q) ------------------------------
__global__ __launch_bounds__(256) void attnB_kernel(
    const unsigned short* __restrict__ Kr,
    const unsigned short* __restrict__ Vt,
    const float* __restrict__ X, const float* __restrict__ Wq,
    const float* __restrict__ bq, float* __restrict__ out) {
  __shared__ __align__(16) unsigned short Kl[64 * 72];
  __shared__ __align__(16) unsigned short Vl[64 * 72];
  __shared__ __align__(16) unsigned short Pl[4 * 16 * 72];
  const int tid = threadIdx.x;
  const int w   = tid >> 6;
  const int ln  = tid & 63;
  const int l15 = ln & 15;
  const int l4  = ln >> 4;
  const int b   = blockIdx.y;
  const int q0  = blockIdx.x * 64;
  const int qrow = q0 + w * 16;
  const f32x4 zero4 = {0.f, 0.f, 0.f, 0.f};
  unsigned short* Pw = &Pl[w * 16 * 72];

  f32x4 accq[4];
  #pragma unroll
  for (int i = 0; i < 4; ++i) accq[i] = zero4;
  const int wn = tid & 63;
  const int wk = (tid >> 6) * 16;
  for (int kb = 0; kb < 16; ++kb) {
    __syncthreads();
    #pragma unroll
    for (int p = 0; p < 4; ++p) {
      int chunk = tid + p * 256;
      int r = chunk >> 4, c4 = chunk & 15;
      const float4 xv = *reinterpret_cast<const float4*>(
          X + ((size_t)b * 4096 + q0 + r) * 1024 + kb * 64 + c4 * 4);
      bf16x4 o;
      o[0] = (short)f2bf(xv.x); o[1] = (short)f2bf(xv.y);
      o[2] = (short)f2bf(xv.z); o[3] = (short)f2bf(xv.w);
      *reinterpret_cast<bf16x4*>(&Kl[r * 72 + c4 * 4]) = o;
    }
    bf16x8 w0, w1;
    #pragma unroll
    for (int j = 0; j < 8; ++j)
      w0[j] = (short)f2bf(Wq[(size_t)(kb * 64 + wk + j) * 64 + wn]);
    #pragma unroll
    for (int j = 0; j < 8; ++j)
      w1[j] = (short)f2bf(Wq[(size_t)(kb * 64 + wk + 8 + j) * 64 + wn]);
    *reinterpret_cast<bf16x8*>(&Vl[wn * 72 + wk])     = w0;
    *reinterpret_cast<bf16x8*>(&Vl[wn * 72 + wk + 8]) = w1;
    __syncthreads();
    bf16x8 a0 = *reinterpret_cast<const bf16x8*>(&Kl[(w * 16 + l15) * 72 + l4 * 8]);
    bf16x8 a1 = *reinterpret_cast<const bf16x8*>(&Kl[(w * 16 + l15) * 72 + 32 + l4 * 8]);
    #pragma unroll
    for (int nt = 0; nt < 4; ++nt) {
      bf16x8 b0 = *reinterpret_cast<const bf16x8*>(&Vl[(nt * 16 + l15) * 72 + l4 * 8]);
      bf16x8 b1 = *reinterpret_cast<const bf16x8*>(&Vl[(nt * 16 + l15) * 72 + 32 + l4 * 8]);
      accq[nt] = __builtin_amdgcn_mfma_f32_16x16x32_bf16(a0, b0, accq[nt], 0, 0, 0);
      accq[nt] = __builtin_amdgcn_mfma_f32_16x16x32_bf16(a1, b1, accq[nt], 0, 0, 0);
    }
  }
  #pragma unroll
  for (int nt = 0; nt < 4; ++nt) {
    int h = nt * 16 + l15;
    #pragma unroll
    for (int r = 0; r < 4; ++r)
      Pw[(l4 * 4 + r) * 72 + h] = f2bf((accq[nt][r] + bq[h]) * 0.125f);
  }
  asm volatile("s_waitcnt lgkmcnt(0)" ::: "memory");
  __builtin_amdgcn_sched_barrier(0);
  bf16x8 qa0 = *reinterpret_cast<const bf16x8*>(&Pw[l15 * 72 + l4 * 8]);
  bf16x8 qa1 = *reinterpret_cast<const bf16x8*>(&Pw[l15 * 72 + 32 + l4 * 8]);

  f32x4 acco[4];
  #pragma unroll
  for (int i = 0; i < 4; ++i) acco[i] = zero4;
  float mrow[4] = {-1e30f, -1e30f, -1e30f, -1e30f};
  float lrow[4] = {0.f, 0.f, 0.f, 0.f};

  const int ktmax = blockIdx.x;
  for (int kt = 0; kt <= ktmax; ++kt) {
    const int kv0 = kt * 64;
    __syncthreads();
    #pragma unroll
    for (int p = 0; p < 2; ++p) {
      int chunk = tid + p * 256;
      int r = chunk >> 3, c8 = chunk & 7;
      *reinterpret_cast<bf16x8*>(&Kl[r * 72 + c8 * 8]) =
          *reinterpret_cast<const bf16x8*>(Kr + ((size_t)b * 4096 + kv0 + r) * 64 + c8 * 8);
      *reinterpret_cast<bf16x8*>(&Vl[r * 72 + c8 * 8]) =
          *reinterpret_cast<const bf16x8*>(Vt + ((size_t)b * 64 + r) * 4096 + kv0 + c8 * 8);
    }
    __syncthreads();
    f32x4 s[4];
    #pragma unroll
    for (int i = 0; i < 4; ++i) s[i] = zero4;
    #pragma unroll
    for (int nt = 0; nt < 4; ++nt) {
      bf16x8 k0 = *reinterpret_cast<const bf16x8*>(&Kl[(nt * 16 + l15) * 72 + l4 * 8]);
      bf16x8 k1 = *reinterpret_cast<const bf16x8*>(&Kl[(nt * 16 + l15) * 72 + 32 + l4 * 8]);
      s[nt] = __builtin_amdgcn_mfma_f32_16x16x32_bf16(qa0, k0, s[nt], 0, 0, 0);
      s[nt] = __builtin_amdgcn_mfma_f32_16x16x32_bf16(qa1, k1, s[nt], 0, 0, 0);
    }
    if (kt == ktmax) {
      #pragma unroll
      for (int nt = 0; nt < 4; ++nt) {
        int kv_g = kv0 + nt * 16 + l15;
        #pragma unroll
        for (int r = 0; r < 4; ++r) {
          int q_g = qrow + l4 * 4 + r;
          if (kv_g > q_g) s[nt][r] = -1e30f;
        }
      }
    }
    #pragma unroll
    for (int r = 0; r < 4; ++r) {
      float t = fmaxf(fmaxf(s[0][r], s[1][r]), fmaxf(s[2][r], s[3][r]));
      t = fmaxf(t, __shfl_xor(t, 1));
      t = fmaxf(t, __shfl_xor(t, 2));
      t = fmaxf(t, __shfl_xor(t, 4));
      t = fmaxf(t, __shfl_xor(t, 8));
      float mnew = fmaxf(mrow[r], t);
      float cc = __expf(mrow[r] - mnew);
      mrow[r] = mnew;
      lrow[r] *= cc;
      acco[0][r] *= cc; acco[1][r] *= cc; acco[2][r] *= cc; acco[3][r] *= cc;
    }
    #pragma unroll
    for (int nt = 0; nt < 4; ++nt) {
      #pragma unroll
      for (int r = 0; r < 4; ++r) {
        float p = __expf(s[nt][r] - mrow[r]);
        s[nt][r] = p;
        Pw[(l4 * 4 + r) * 72 + nt * 16 + l15] = f2bf(p);
      }
    }
    #pragma unroll
    for (int r = 0; r < 4; ++r) {
      float t = s[0][r] + s[1][r] + s[2][r] + s[3][r];
      t += __shfl_xor(t, 1);
      t += __shfl_xor(t, 2);
      t += __shfl_xor(t, 4);
      t += __shfl_xor(t, 8);
      lrow[r] += t;
    }
    asm volatile("s_waitcnt lgkmcnt(0)" ::: "memory");
    __builtin_amdgcn_sched_barrier(0);
    #pragma unroll
    for (int ks = 0; ks < 2; ++ks) {
      bf16x8 pa = *reinterpret_cast<const bf16x8*>(&Pw[l15 * 72 + ks * 32 + l4 * 8]);
      #pragma unroll
      for (int ht = 0; ht < 4; ++ht) {
        bf16x8 vf = *reinterpret_cast<const bf16x8*>(&Vl[(ht * 16 + l15) * 72 + ks * 32 + l4 * 8]);
        acco[ht] = __builtin_amdgcn_mfma_f32_16x16x32_bf16(pa, vf, acco[ht], 0, 0, 0);
      }
    }
  }
  float* ob = out + ((size_t)b * 4096 + qrow) * 64;
  #pragma unroll
  for (int ht = 0; ht < 4; ++ht) {
    #pragma unroll
    for (int r = 0; r < 4; ++r) {
      ob[(l4 * 4 + r) * 64 + ht * 16 + l15] = acco[ht][r] / lrow[r];
    }
  }
}

extern "C" void kernel_launch(void* const* d_in, const int* in_sizes, int n_in,
                              void* d_out, int out_size, void* d_ws, size_t ws_size,
                              hipStream_t stream) {
  const float* X  = (const float*)d_in[0];
  const float* Wk = (const float*)d_in[1];
  const float* bk = (const float*)d_in[2];
  const float* Wq = (const float*)d_in[3];
  const float* bq = (const float*)d_in[4];
  const float* Wv = (const float*)d_in[5];
  const float* bv = (const float*)d_in[6];
  float* out = (float*)d_out;

  char* ws = (char*)d_ws;
  const size_t SZ = 2097152;  // one bf16 [B*T][64] buffer
  unsigned short* Kr = (unsigned short*)(ws);
  unsigned short* Vt = (unsigned short*)(ws + SZ);

  if (ws_size >= 3 * SZ) {
    unsigned short* Qs = (unsigned short*)(ws + 2 * SZ);
    proj_kernel<true><<<256, 256, 0, stream>>>(X, Wk, Wq, Wv, bk, bq, bv, Kr, Qs, Vt);
    attn3_kernel<<<512, 256, 0, stream>>>(Qs, Kr, Vt, out);
  } else {
    proj_kernel<false><<<256, 256, 0, stream>>>(X, Wk, Wq, Wv, bk, bq, bv, Kr, nullptr, Vt);
    attnB_kernel<<<dim3(64, 4), 256, 0, stream>>>(Kr, Vt, X, Wq, bq, out);
  }
}

// Round 6
// 77.240 us; speedup vs baseline: 2.5955x; 1.2900x over previous
//
#include <hip/hip_runtime.h>

// AttentionHead: B=4, T=4096, C=1024, H=64, causal softmax(QK^T/8)V
// R6: attn4 = swapped QK^T (D=S^T, row-softmax lane-local: 2 shfls/iter),
// PV via mfma_16x16x16 with P kept in registers (no P LDS round-trip).
// proj2 = 512-thread blocks (2 waves/SIMD). Plan B fallback unchanged.

using bf16x8 = __attribute__((ext_vector_type(8))) short;
using bf16x4 = __attribute__((ext_vector_type(4))) short;
using f32x4  = __attribute__((ext_vector_type(4))) float;

#define QSCALE 0.1803368867f  // 0.125 * log2(e): softmax in exp2 domain

__device__ __forceinline__ unsigned short f2bf(float f) {
  union { float f; unsigned int u; } v; v.f = f;
  unsigned int r = v.u + 0x7fffu + ((v.u >> 16) & 1u);  // RNE
  return (unsigned short)(r >> 16);
}

__device__ __forceinline__ float fexp2(float x) {
#if __has_builtin(__builtin_amdgcn_exp2f)
  return __builtin_amdgcn_exp2f(x);
#else
  float r; asm("v_exp_f32 %0, %1" : "=v"(r) : "v"(x)); return r;
#endif
}

__device__ __forceinline__ void gl_lds16(const void* g, void* l) {
  __builtin_amdgcn_global_load_lds(
      (const __attribute__((address_space(1))) void*)g,
      (__attribute__((address_space(3))) void*)l, 16, 0, 0);
}

__device__ __forceinline__ f32x4 mfma16(bf16x4 a, bf16x4 b, f32x4 c) {
#if __has_builtin(__builtin_amdgcn_mfma_f32_16x16x16bf16_1k)
  return __builtin_amdgcn_mfma_f32_16x16x16bf16_1k(a, b, c, 0, 0, 0);
#else
  f32x4 d;
  asm volatile("v_mfma_f32_16x16x16_bf16 %0, %1, %2, %3"
               : "=v"(d) : "v"(a), "v"(b), "v"(c));
  return d;
#endif
}

// ---- proj2 (Plan A): 64 rows x 192 cols per block, 8 waves ------------
__global__ __launch_bounds__(512) void proj2_kernel(
    const float* __restrict__ X,  const float* __restrict__ Wk,
    const float* __restrict__ Wq, const float* __restrict__ Wv,
    const float* __restrict__ bk, const float* __restrict__ bq,
    const float* __restrict__ bv, unsigned short* __restrict__ Kr,
    unsigned short* __restrict__ Qs, unsigned short* __restrict__ Vt) {
  __shared__ __align__(16) unsigned short Xl[64 * 72];
  __shared__ __align__(16) unsigned short Wl[192 * 72];
  const int tid = threadIdx.x;
  const int m0  = blockIdx.x * 64;
  const int w   = tid >> 6;      // 0..7
  const int mt  = w & 3;         // m-tile (16 rows)
  const int nh  = w >> 2;        // n-half (96 cols)
  const int ln  = tid & 63;
  const int l15 = ln & 15;
  const int l4  = ln >> 4;
  const int wn  = tid & 63;      // W staging: lane = n (coalesced)
  const int wk8 = (tid >> 6) * 8;
  const f32x4 zero4 = {0.f, 0.f, 0.f, 0.f};

  f32x4 acc[6];
  #pragma unroll
  for (int i = 0; i < 6; ++i) acc[i] = zero4;

  for (int kb = 0; kb < 16; ++kb) {
    __syncthreads();
    #pragma unroll
    for (int p = 0; p < 2; ++p) {   // stage X 64x64 fp32 -> bf16
      int chunk = tid + p * 512;
      int r = chunk >> 4, c4 = chunk & 15;
      const float4 xv = *reinterpret_cast<const float4*>(
          X + (size_t)(m0 + r) * 1024 + kb * 64 + c4 * 4);
      bf16x4 o;
      o[0] = (short)f2bf(xv.x); o[1] = (short)f2bf(xv.y);
      o[2] = (short)f2bf(xv.z); o[3] = (short)f2bf(xv.w);
      *reinterpret_cast<bf16x4*>(&Xl[r * 72 + c4 * 4]) = o;
    }
    #pragma unroll
    for (int c = 0; c < 3; ++c) {   // stage W transposed: Wl[n][k]
      const float* Wsrc = (c == 0) ? Wk : ((c == 1) ? Wq : Wv);
      bf16x8 w0;
      #pragma unroll
      for (int j = 0; j < 8; ++j)
        w0[j] = (short)f2bf(Wsrc[(size_t)(kb * 64 + wk8 + j) * 64 + wn]);
      *reinterpret_cast<bf16x8*>(&Wl[(c * 64 + wn) * 72 + wk8]) = w0;
    }
    __syncthreads();
    bf16x8 a0 = *reinterpret_cast<const bf16x8*>(&Xl[(mt * 16 + l15) * 72 + l4 * 8]);
    bf16x8 a1 = *reinterpret_cast<const bf16x8*>(&Xl[(mt * 16 + l15) * 72 + 32 + l4 * 8]);
    #pragma unroll
    for (int i = 0; i < 6; ++i) {
      int row = nh * 96 + i * 16 + l15;
      bf16x8 b0 = *reinterpret_cast<const bf16x8*>(&Wl[row * 72 + l4 * 8]);
      bf16x8 b1 = *reinterpret_cast<const bf16x8*>(&Wl[row * 72 + 32 + l4 * 8]);
      acc[i] = __builtin_amdgcn_mfma_f32_16x16x32_bf16(a0, b0, acc[i], 0, 0, 0);
      acc[i] = __builtin_amdgcn_mfma_f32_16x16x32_bf16(a1, b1, acc[i], 0, 0, 0);
    }
  }
  #pragma unroll
  for (int i = 0; i < 6; ++i) {
    int j = nh * 96 + i * 16 + l15;
    int mr0 = m0 + mt * 16 + l4 * 4;
    if (j < 64) {
      #pragma unroll
      for (int r = 0; r < 4; ++r)
        Kr[(size_t)(mr0 + r) * 64 + j] = f2bf(acc[i][r] + bk[j]);
    } else if (j < 128) {
      int jq = j - 64;
      #pragma unroll
      for (int r = 0; r < 4; ++r)
        Qs[(size_t)(mr0 + r) * 64 + jq] = f2bf((acc[i][r] + bq[jq]) * QSCALE);
    } else {
      int h = j - 128;
      int bb = mr0 >> 12, t0 = mr0 & 4095;
      ushort4 o;
      o.x = f2bf(acc[i][0] + bv[h]); o.y = f2bf(acc[i][1] + bv[h]);
      o.z = f2bf(acc[i][2] + bv[h]); o.w = f2bf(acc[i][3] + bv[h]);
      *reinterpret_cast<ushort4*>(&Vt[((size_t)(bb * 64 + h)) * 4096 + t0]) = o;
    }
  }
}

// ---- attn4: 512 blocks, 4 waves = 2 kv-parity pairs; swapped QK^T -----
__global__ __launch_bounds__(256) void attn4_kernel(
    const unsigned short* __restrict__ Qs,
    const unsigned short* __restrict__ Kr,
    const unsigned short* __restrict__ Vt,
    float* __restrict__ out) {
  __shared__ __align__(16) unsigned short Kl[2][2][64 * 64];  // [pair][buf]
  __shared__ __align__(16) unsigned short Vl[2][2][64 * 64];  // [h][kv] swz
  const int tid = threadIdx.x;
  const int w    = tid >> 6;         // 0..3
  const int pair = w >> 1;           // kv parity
  const int qh   = w & 1;            // q half (16 rows)
  const int ln  = tid & 63;
  const int l15 = ln & 15;
  const int l4  = ln >> 4;
  const int bid = blockIdx.x;
  const int qt  = 127 - (bid >> 2);  // longest-first
  const int b   = bid & 3;           // one batch per XCD
  const int q0  = qt * 32;
  const int qrow = q0 + qh * 16;
  const int ntiles = (qt >> 1) + 1;
  const int ITER = (ntiles + 1) >> 1;
  const f32x4 zero4 = {0.f, 0.f, 0.f, 0.f};

  const int lswz16 = (ln ^ (ln >> 3)) * 16;           // K src swizzle
  const int vrow_l = ln >> 3;
  const int vcol_l = ((ln & 7) ^ (ln >> 3)) * 16;     // V src swizzle
  const char* Kbase = (const char*)Kr + (size_t)b * 4096 * 128;
  const char* Vbase = (const char*)Vt + (size_t)b * 64 * 8192;

  auto stage = [&](int buf, int t) {
    if (qh == 0) {
      const char* src = Kbase + (size_t)t * 8192 + lswz16;
      #pragma unroll
      for (int j = 0; j < 8; ++j)
        gl_lds16(src + j * 1024, (char*)&Kl[pair][buf][0] + j * 1024);
    } else {
      const char* src = Vbase + (size_t)t * 128 + (size_t)vrow_l * 8192 + vcol_l;
      #pragma unroll
      for (int j = 0; j < 8; ++j)
        gl_lds16(src + (size_t)j * 8 * 8192, (char*)&Vl[pair][buf][0] + j * 1024);
    }
  };

  // Q as B-fragment: n = q = l15, k = h = 8*l4+i (two 32-halves)
  const unsigned short* Qbase = Qs + ((size_t)b * 4096 + qrow + l15) * 64;
  const bf16x8 qa0 = *reinterpret_cast<const bf16x8*>(Qbase + l4 * 8);
  const bf16x8 qa1 = *reinterpret_cast<const bf16x8*>(Qbase + 32 + l4 * 8);

  f32x4 acco[4];   // O^T: acco[ht][r] = O[h=ht*16+4*l4+r][q=l15]
  #pragma unroll
  for (int i = 0; i < 4; ++i) acco[i] = zero4;
  float mreg = -1e30f, lreg = 0.f;

  int cur = 0;
  if (pair < ntiles) stage(0, pair);
  asm volatile("s_waitcnt vmcnt(0)" ::: "memory");
  __syncthreads();

  for (int it = 0; it < ITER; ++it) {
    const int t  = 2 * it + pair;
    const int tn = t + 2;
    if (tn < ntiles) stage(cur ^ 1, tn);

    if (t < ntiles) {
      // ---- S^T = K Q^T : s[nt][r] = S[kv=nt*16+4*l4+r][q=l15]
      f32x4 s[4];
      #pragma unroll
      for (int i = 0; i < 4; ++i) s[i] = zero4;
      __builtin_amdgcn_s_setprio(1);
      #pragma unroll
      for (int nt = 0; nt < 4; ++nt) {
        const int krow = nt * 16 + l15;
        const unsigned short* kp = &Kl[pair][cur][krow * 64];
        bf16x8 k0 = *reinterpret_cast<const bf16x8*>(kp + ((l4 ^ (krow & 7)) << 3));
        bf16x8 k1 = *reinterpret_cast<const bf16x8*>(kp + (((l4 + 4) ^ (krow & 7)) << 3));
        s[nt] = __builtin_amdgcn_mfma_f32_16x16x32_bf16(k0, qa0, s[nt], 0, 0, 0);
        s[nt] = __builtin_amdgcn_mfma_f32_16x16x32_bf16(k1, qa1, s[nt], 0, 0, 0);
      }
      __builtin_amdgcn_s_setprio(0);

      if (t == ntiles - 1) {  // causal mask: kv_local > q_local
        const int qm = qrow + l15 - t * 64;
        #pragma unroll
        for (int nt = 0; nt < 4; ++nt)
          #pragma unroll
          for (int r = 0; r < 4; ++r)
            if (nt * 16 + 4 * l4 + r > qm) s[nt][r] = -1e30f;
      }
      // ---- online softmax: lane owns one q-row segment (16 kv values)
      float x0 = fmaxf(fmaxf(s[0][0], s[0][1]), fmaxf(s[0][2], s[0][3]));
      float x1 = fmaxf(fmaxf(s[1][0], s[1][1]), fmaxf(s[1][2], s[1][3]));
      float x2 = fmaxf(fmaxf(s[2][0], s[2][1]), fmaxf(s[2][2], s[2][3]));
      float x3 = fmaxf(fmaxf(s[3][0], s[3][1]), fmaxf(s[3][2], s[3][3]));
      float tmx = fmaxf(fmaxf(x0, x1), fmaxf(x2, x3));
      tmx = fmaxf(tmx, __shfl_xor(tmx, 16));
      tmx = fmaxf(tmx, __shfl_xor(tmx, 32));
      float mnew = fmaxf(mreg, tmx);
      float cc = fexp2(mreg - mnew);
      mreg = mnew;
      lreg *= cc;
      #pragma unroll
      for (int ht = 0; ht < 4; ++ht)
        #pragma unroll
        for (int r = 0; r < 4; ++r) acco[ht][r] *= cc;

      bf16x4 pa[4];
      float sum = 0.f;
      #pragma unroll
      for (int nt = 0; nt < 4; ++nt) {
        #pragma unroll
        for (int r = 0; r < 4; ++r) {
          float p = fexp2(s[nt][r] - mreg);
          s[nt][r] = p;
          pa[nt][r] = (short)f2bf(p);
        }
        sum += (s[nt][0] + s[nt][1]) + (s[nt][2] + s[nt][3]);
      }
      sum += __shfl_xor(sum, 16);
      sum += __shfl_xor(sum, 32);
      lreg += sum;

      // ---- O^T += V^T P^T : A = V-frag (ds_read_b64), B = pa (registers)
      __builtin_amdgcn_s_setprio(1);
      #pragma unroll
      for (int ht = 0; ht < 4; ++ht) {
        const int vrow = ht * 16 + l15;
        const char* vp = (const char*)&Vl[pair][cur][0] + vrow * 128 + ((l4 & 1) << 3);
        #pragma unroll
        for (int nt = 0; nt < 4; ++nt) {
          bf16x4 vf = *reinterpret_cast<const bf16x4*>(
              vp + ((((2 * nt + (l4 >> 1)) ^ (l15 & 7))) << 4));
          acco[ht] = mfma16(vf, pa[nt], acco[ht]);
        }
      }
      __builtin_amdgcn_s_setprio(0);
    }

    if (it + 1 < ITER) {
      asm volatile("s_waitcnt vmcnt(0)" ::: "memory");
      __syncthreads();
      cur ^= 1;
    }
  }

  // ---- merge pair 1 into pair 0 (exact, fp32) via pair-1 staging LDS --
  __syncthreads();
  float* CO = (float*)&Kl[1][qh][0];   // [64 h][16 q] f32 per q-half (4KB)
  float* Cm = (float*)&Vl[1][0][0];    // 32 floats
  float* Cl = Cm + 32;                 // 32 floats
  if (pair == 1) {
    #pragma unroll
    for (int ht = 0; ht < 4; ++ht)
      #pragma unroll
      for (int r = 0; r < 4; ++r)
        CO[(ht * 16 + 4 * l4 + r) * 16 + l15] = acco[ht][r];
    if (l4 == 0) { Cm[qh * 16 + l15] = mreg; Cl[qh * 16 + l15] = lreg; }
  }
  __syncthreads();
  if (pair == 0) {
    float mB = Cm[qh * 16 + l15], lB = Cl[qh * 16 + l15];
    float mM = fmaxf(mreg, mB);
    float aA = fexp2(mreg - mM);
    float aB = fexp2(mB - mM);
    float linv = 1.0f / (lreg * aA + lB * aB);
    float* ob = out + ((size_t)b * 4096 + qrow + l15) * 64;
    #pragma unroll
    for (int ht = 0; ht < 4; ++ht) {
      float4 o;
      o.x = (acco[ht][0] * aA + CO[(ht * 16 + 4 * l4 + 0) * 16 + l15] * aB) * linv;
      o.y = (acco[ht][1] * aA + CO[(ht * 16 + 4 * l4 + 1) * 16 + l15] * aB) * linv;
      o.z = (acco[ht][2] * aA + CO[(ht * 16 + 4 * l4 + 2) * 16 + l15] * aB) * linv;
      o.w = (acco[ht][3] * aA + CO[(ht * 16 + 4 * l4 + 3) * 16 + l15] * aB) * linv;
      *reinterpret_cast<float4*>(ob + ht * 16 + 4 * l4) = o;
    }
  }
}

// ---- Plan-B fallback: old proj (no Q) + attn with Q recompute ---------
template <bool WRITE_Q>
__global__ __launch_bounds__(256) void proj_kernel(
    const float* __restrict__ X,  const float* __restrict__ Wk,
    const float* __restrict__ Wq, const float* __restrict__ Wv,
    const float* __restrict__ bk, const float* __restrict__ bq,
    const float* __restrict__ bv, unsigned short* __restrict__ Kr,
    unsigned short* __restrict__ Qs, unsigned short* __restrict__ Vt) {
  constexpr int NT = WRITE_Q ? 12 : 8;
  constexpr int NC = NT / 4;
  __shared__ __align__(16) unsigned short Xl[64 * 72];
  __shared__ __align__(16) unsigned short Wl[NT * 16 * 72];
  const int tid = threadIdx.x;
  const int m0  = blockIdx.x * 64;
  const int w   = tid >> 6;
  const int ln  = tid & 63;
  const int l15 = ln & 15;
  const int l4  = ln >> 4;
  const f32x4 zero4 = {0.f, 0.f, 0.f, 0.f};
  f32x4 acc[NT];
  #pragma unroll
  for (int i = 0; i < NT; ++i) acc[i] = zero4;
  const int wn = tid & 63;
  const int wk = (tid >> 6) * 16;
  for (int kb = 0; kb < 16; ++kb) {
    __syncthreads();
    #pragma unroll
    for (int p = 0; p < 4; ++p) {
      int chunk = tid + p * 256;
      int r = chunk >> 4, c4 = chunk & 15;
      const float4 xv = *reinterpret_cast<const float4*>(
          X + (size_t)(m0 + r) * 1024 + kb * 64 + c4 * 4);
      bf16x4 o;
      o[0] = (short)f2bf(xv.x); o[1] = (short)f2bf(xv.y);
      o[2] = (short)f2bf(xv.z); o[3] = (short)f2bf(xv.w);
      *reinterpret_cast<bf16x4*>(&Xl[r * 72 + c4 * 4]) = o;
    }
    #pragma unroll
    for (int c = 0; c < NC; ++c) {
      const float* Wsrc = (c == 0) ? Wk : ((WRITE_Q && c == 1) ? Wq : Wv);
      bf16x8 w0, w1;
      #pragma unroll
      for (int j = 0; j < 8; ++j)
        w0[j] = (short)f2bf(Wsrc[(size_t)(kb * 64 + wk + j) * 64 + wn]);
      #pragma unroll
      for (int j = 0; j < 8; ++j)
        w1[j] = (short)f2bf(Wsrc[(size_t)(kb * 64 + wk + 8 + j) * 64 + wn]);
      *reinterpret_cast<bf16x8*>(&Wl[(c * 64 + wn) * 72 + wk])     = w0;
      *reinterpret_cast<bf16x8*>(&Wl[(c * 64 + wn) * 72 + wk + 8]) = w1;
    }
    __syncthreads();
    bf16x8 a0 = *reinterpret_cast<const bf16x8*>(&Xl[(w * 16 + l15) * 72 + l4 * 8]);
    bf16x8 a1 = *reinterpret_cast<const bf16x8*>(&Xl[(w * 16 + l15) * 72 + 32 + l4 * 8]);
    #pragma unroll
    for (int nt = 0; nt < NT; ++nt) {
      bf16x8 b0 = *reinterpret_cast<const bf16x8*>(&Wl[(nt * 16 + l15) * 72 + l4 * 8]);
      bf16x8 b1 = *reinterpret_cast<const bf16x8*>(&Wl[(nt * 16 + l15) * 72 + 32 + l4 * 8]);
      acc[nt] = __builtin_amdgcn_mfma_f32_16x16x32_bf16(a0, b0, acc[nt], 0, 0, 0);
      acc[nt] = __builtin_amdgcn_mfma_f32_16x16x32_bf16(a1, b1, acc[nt], 0, 0, 0);
    }
  }
  #pragma unroll
  for (int nt = 0; nt < NT; ++nt) {
    int j = nt * 16 + l15;
    #pragma unroll
    for (int r = 0; r < 4; ++r) {
      int m = m0 + w * 16 + l4 * 4 + r;
      float v = acc[nt][r];
      if (nt < 4) {
        Kr[(size_t)m * 64 + j] = f2bf(v + bk[j]);
      } else if (WRITE_Q && nt < 8) {
        Qs[(size_t)m * 64 + (j - 64)] = f2bf((v + bq[j - 64]) * QSCALE);
      } else {
        int h = j - (WRITE_Q ? 128 : 64);
        int bb = m >> 12, t = m & 4095;
        Vt[((size_t)(bb * 64 + h)) * 4096 + t] = f2bf(v + bv[h]);
      }
    }
  }
}

__global__ __launch_bounds__(256) void attnB_kernel(
    const unsigned short* __restrict__ Kr,
    const unsigned short* __restrict__ Vt,
    const float* __restrict__ X, const float* __restrict__ Wq,
    const float* __restrict__ bq, float* __restrict__ out) {
  __shared__ __align__(16) unsigned short Kl[64 * 72];
  __shared__ __align__(16) unsigned short Vl[64 * 72];
  __shared__ __align__(16) unsigned short Pl[4 * 16 * 72];
  const int tid = threadIdx.x;
  const int w   = tid >> 6;
  const int ln  = tid & 63;
  const int l15 = ln & 15;
  const int l4  = ln >> 4;
  const int b   = blockIdx.y;
  const int q0  = blockIdx.x * 64;
  const int qrow = q0 + w * 16;
  const f32x4 zero4 = {0.f, 0.f, 0.f, 0.f};
  unsigned short* Pw = &Pl[w * 16 * 72];
  f32x4 accq[4];
  #pragma unroll
  for (int i = 0; i < 4; ++i) accq[i] = zero4;
  const int wn = tid & 63;
  const int wk = (tid >> 6) * 16;
  for (int kb = 0; kb < 16; ++kb) {
    __syncthreads();
    #pragma unroll
    for (int p = 0; p < 4; ++p) {
      int chunk = tid + p * 256;
      int r = chunk >> 4, c4 = chunk & 15;
      const float4 xv = *reinterpret_cast<const float4*>(
          X + ((size_t)b * 4096 + q0 + r) * 1024 + kb * 64 + c4 * 4);
      bf16x4 o;
      o[0] = (short)f2bf(xv.x); o[1] = (short)f2bf(xv.y);
      o[2] = (short)f2bf(xv.z); o[3] = (short)f2bf(xv.w);
      *reinterpret_cast<bf16x4*>(&Kl[r * 72 + c4 * 4]) = o;
    }
    bf16x8 w0, w1;
    #pragma unroll
    for (int j = 0; j < 8; ++j)
      w0[j] = (short)f2bf(Wq[(size_t)(kb * 64 + wk + j) * 64 + wn]);
    #pragma unroll
    for (int j = 0; j < 8; ++j)
      w1[j] = (short)f2bf(Wq[(size_t)(kb * 64 + wk + 8 + j) * 64 + wn]);
    *reinterpret_cast<bf16x8*>(&Vl[wn * 72 + wk])     = w0;
    *reinterpret_cast<bf16x8*>(&Vl[wn * 72 + wk + 8]) = w1;
    __syncthreads();
    bf16x8 a0 = *reinterpret_cast<const bf16x8*>(&Kl[(w * 16 + l15) * 72 + l4 * 8]);
    bf16x8 a1 = *reinterpret_cast<const bf16x8*>(&Kl[(w * 16 + l15) * 72 + 32 + l4 * 8]);
    #pragma unroll
    for (int nt = 0; nt < 4; ++nt) {
      bf16x8 b0 = *reinterpret_cast<const bf16x8*>(&Vl[(nt * 16 + l15) * 72 + l4 * 8]);
      bf16x8 b1 = *reinterpret_cast<const bf16x8*>(&Vl[(nt * 16 + l15) * 72 + 32 + l4 * 8]);
      accq[nt] = __builtin_amdgcn_mfma_f32_16x16x32_bf16(a0, b0, accq[nt], 0, 0, 0);
      accq[nt] = __builtin_amdgcn_mfma_f32_16x16x32_bf16(a1, b1, accq[nt], 0, 0, 0);
    }
  }
  #pragma unroll
  for (int nt = 0; nt < 4; ++nt) {
    int h = nt * 16 + l15;
    #pragma unroll
    for (int r = 0; r < 4; ++r)
      Pw[(l4 * 4 + r) * 72 + h] = f2bf((accq[nt][r] + bq[h]) * 0.125f);
  }
  asm volatile("s_waitcnt lgkmcnt(0)" ::: "memory");
  __builtin_amdgcn_sched_barrier(0);
  bf16x8 qa0 = *reinterpret_cast<const bf16x8*>(&Pw[l15 * 72 + l4 * 8]);
  bf16x8 qa1 = *reinterpret_cast<const bf16x8*>(&Pw[l15 * 72 + 32 + l4 * 8]);
  f32x4 acco[4];
  #pragma unroll
  for (int i = 0; i < 4; ++i) acco[i] = zero4;
  float mrow[4] = {-1e30f, -1e30f, -1e30f, -1e30f};
  float lrow[4] = {0.f, 0.f, 0.f, 0.f};
  const int ktmax = blockIdx.x;
  for (int kt = 0; kt <= ktmax; ++kt) {
    const int kv0 = kt * 64;
    __syncthreads();
    #pragma unroll
    for (int p = 0; p < 2; ++p) {
      int chunk = tid + p * 256;
      int r = chunk >> 3, c8 = chunk & 7;
      *reinterpret_cast<bf16x8*>(&Kl[r * 72 + c8 * 8]) =
          *reinterpret_cast<const bf16x8*>(Kr + ((size_t)b * 4096 + kv0 + r) * 64 + c8 * 8);
      *reinterpret_cast<bf16x8*>(&Vl[r * 72 + c8 * 8]) =
          *reinterpret_cast<const bf16x8*>(Vt + ((size_t)b * 64 + r) * 4096 + kv0 + c8 * 8);
    }
    __syncthreads();
    f32x4 s[4];
    #pragma unroll
    for (int i = 0; i < 4; ++i) s[i] = zero4;
    #pragma unroll
    for (int nt = 0; nt < 4; ++nt) {
      bf16x8 k0 = *reinterpret_cast<const bf16x8*>(&Kl[(nt * 16 + l15) * 72 + l4 * 8]);
      bf16x8 k1 = *reinterpret_cast<const bf16x8*>(&Kl[(nt * 16 + l15) * 72 + 32 + l4 * 8]);
      s[nt] = __builtin_amdgcn_mfma_f32_16x16x32_bf16(qa0, k0, s[nt], 0, 0, 0);
      s[nt] = __builtin_amdgcn_mfma_f32_16x16x32_bf16(qa1, k1, s[nt], 0, 0, 0);
    }
    if (kt == ktmax) {
      #pragma unroll
      for (int nt = 0; nt < 4; ++nt) {
        int kv_g = kv0 + nt * 16 + l15;
        #pragma unroll
        for (int r = 0; r < 4; ++r) {
          int q_g = qrow + l4 * 4 + r;
          if (kv_g > q_g) s[nt][r] = -1e30f;
        }
      }
    }
    #pragma unroll
    for (int r = 0; r < 4; ++r) {
      float t = fmaxf(fmaxf(s[0][r], s[1][r]), fmaxf(s[2][r], s[3][r]));
      t = fmaxf(t, __shfl_xor(t, 1));
      t = fmaxf(t, __shfl_xor(t, 2));
      t = fmaxf(t, __shfl_xor(t, 4));
      t = fmaxf(t, __shfl_xor(t, 8));
      float mnew = fmaxf(mrow[r], t);
      float cc = __expf(mrow[r] - mnew);
      mrow[r] = mnew;
      lrow[r] *= cc;
      acco[0][r] *= cc; acco[1][r] *= cc; acco[2][r] *= cc; acco[3][r] *= cc;
    }
    #pragma unroll
    for (int nt = 0; nt < 4; ++nt) {
      #pragma unroll
      for (int r = 0; r < 4; ++r) {
        float p = __expf(s[nt][r] - mrow[r]);
        s[nt][r] = p;
        Pw[(l4 * 4 + r) * 72 + nt * 16 + l15] = f2bf(p);
      }
    }
    #pragma unroll
    for (int r = 0; r < 4; ++r) {
      float t = s[0][r] + s[1][r] + s[2][r] + s[3][r];
      t += __shfl_xor(t, 1);
      t += __shfl_xor(t, 2);
      t += __shfl_xor(t, 4);
      t += __shfl_xor(t, 8);
      lrow[r] += t;
    }
    asm volatile("s_waitcnt lgkmcnt(0)" ::: "memory");
    __builtin_amdgcn_sched_barrier(0);
    #pragma unroll
    for (int ks = 0; ks < 2; ++ks) {
      bf16x8 pa = *reinterpret_cast<const bf16x8*>(&Pw[l15 * 72 + ks * 32 + l4 * 8]);
      #pragma unroll
      for (int ht = 0; ht < 4; ++ht) {
        bf16x8 vf = *reinterpret_cast<const bf16x8*>(&Vl[(ht * 16 + l15) * 72 + ks * 32 + l4 * 8]);
        acco[ht] = __builtin_amdgcn_mfma_f32_16x16x32_bf16(pa, vf, acco[ht], 0, 0, 0);
      }
    }
  }
  float* ob = out + ((size_t)b * 4096 + qrow) * 64;
  #pragma unroll
  for (int ht = 0; ht < 4; ++ht) {
    #pragma unroll
    for (int r = 0; r < 4; ++r) {
      ob[(l4 * 4 + r) * 64 + ht * 16 + l15] = acco[ht][r] / lrow[r];
    }
  }
}

extern "C" void kernel_launch(void* const* d_in, const int* in_sizes, int n_in,
                              void* d_out, int out_size, void* d_ws, size_t ws_size,
                              hipStream_t stream) {
  const float* X  = (const float*)d_in[0];
  const float* Wk = (const float*)d_in[1];
  const float* bk = (const float*)d_in[2];
  const float* Wq = (const float*)d_in[3];
  const float* bq = (const float*)d_in[4];
  const float* Wv = (const float*)d_in[5];
  const float* bv = (const float*)d_in[6];
  float* out = (float*)d_out;

  char* ws = (char*)d_ws;
  const size_t SZ = 2097152;  // one bf16 [B*T][64] buffer
  unsigned short* Kr = (unsigned short*)(ws);
  unsigned short* Vt = (unsigned short*)(ws + SZ);

  if (ws_size >= 3 * SZ) {
    unsigned short* Qs = (unsigned short*)(ws + 2 * SZ);
    proj2_kernel<<<256, 512, 0, stream>>>(X, Wk, Wq, Wv, bk, bq, bv, Kr, Qs, Vt);
    attn4_kernel<<<512, 256, 0, stream>>>(Qs, Kr, Vt, out);
  } else {
    proj_kernel<false><<<256, 256, 0, stream>>>(X, Wk, Wq, Wv, bk, bq, bv, Kr, nullptr, Vt);
    attnB_kernel<<<dim3(64, 4), 256, 0, stream>>>(Kr, Vt, X, Wq, bq, out);
  }
}